// Round 13
// baseline (75.352 us; speedup 1.0000x reference)
//
#include <hip/hip_runtime.h>
#include <hip/hip_fp16.h>

#define B_    1024
#define T_    256
#define C_    128
#define LMAX  32
#define NEGV  -1e9f
#define GS    34     // g row stride in halves: slot 0 = blank, 1+j = label j

__device__ __forceinline__ float laddexp(float p, float q) {
    float m = fmaxf(p, q);
    float d = fabsf(p - q);
    return m + __logf(1.0f + __expf(-d));
}
__device__ __forceinline__ float dpp_shr1(float v) {  // dest[i]=src[i-1], lane0=NEGV
    int r = __builtin_amdgcn_update_dpp(__float_as_int(NEGV), __float_as_int(v),
                                        0x138, 0xF, 0xF, false);
    return __int_as_float(r);
}
__device__ __forceinline__ float dpp_shl1(float v) {  // dest[i]=src[i+1], lane63=NEGV
    int r = __builtin_amdgcn_update_dpp(__float_as_int(NEGV), __float_as_int(v),
                                        0x130, 0xF, 0xF, false);
    return __int_as_float(r);
}
template<int CTRL>
__device__ __forceinline__ float dpp_mov0(float v) {
    return __int_as_float(__builtin_amdgcn_update_dpp(0, __float_as_int(v),
                                                      CTRL, 0xF, 0xF, true));
}
__device__ __forceinline__ float readlanef(float v, int l) {
    return __int_as_float(__builtin_amdgcn_readlane(__float_as_int(v), l));
}
__device__ __forceinline__ float readlane0f(float v) {
    return __int_as_float(__builtin_amdgcn_readfirstlane(__float_as_int(v)));
}
// per-32-half sum: lane31 = sum(l0..31), lane63 = sum(l32..63)
__device__ __forceinline__ float halfsum_dpp(float v) {
    v += dpp_mov0<0x111>(v); v += dpp_mov0<0x112>(v);
    v += dpp_mov0<0x114>(v); v += dpp_mov0<0x118>(v);
    v += dpp_mov0<0x142>(v);   // row_bcast:15
    return v;
}
__device__ __forceinline__ float halfsum_shfl(float v) {
    #pragma unroll
    for (int off = 16; off; off >>= 1) v += __shfl_xor(v, off);
    return v;
}

// ---------- forward step (R12-verified): lane s holds alpha[s] ---------------
template<bool DPP>
__device__ __forceinline__ void fstep(float& a, float& a64, float lp,
                                      int lane, bool skip) {
    float am1, am2;
    if constexpr (DPP) {
        am1 = dpp_shr1(a);
        am2 = dpp_shr1(am1);
    } else {
        float s1 = __shfl_up(a, 1);
        float s2 = __shfl_up(a, 2);
        am1 = (lane < 1) ? NEGV : s1;
        am2 = (lane < 2) ? NEGV : s2;
    }
    float a63  = readlanef(a, 63);
    float am2e = skip ? am2 : NEGV;
    float m    = fmaxf(fmaxf(a, am1), am2e);
    float r    = m + __logf(__expf(a - m) + __expf(am1 - m) + __expf(am2e - m));
    float lpb  = readlane0f(lp);
    float m2   = fmaxf(a64, a63);
    float r64  = m2 + __logf(__expf(a64 - m2) + __expf(a63 - m2));
    a   = r + lp;
    a64 = r64 + lpb;
}
// ---------- backward step (R12-verified): lane s holds B[s] ------------------
template<bool DPP>
__device__ __forceinline__ void bstep(float& B, float& b64, float lp,
                                      int lane, bool skipT, bool l63) {
    float raw1, bs2;
    if constexpr (DPP) {
        raw1 = dpp_shl1(B);
        bs2  = dpp_shl1(raw1);
    } else {
        float s1 = __shfl_down(B, 1);
        float s2 = __shfl_down(B, 2);
        raw1 = (lane < 63) ? s1 : NEGV;
        bs2  = (lane < 62) ? s2 : NEGV;
    }
    float bs1  = l63 ? b64 : raw1;
    float bs2e = skipT ? bs2 : NEGV;
    float m    = fmaxf(fmaxf(B, bs1), bs2e);
    float r    = m + __logf(__expf(B - m) + __expf(bs1 - m) + __expf(bs2e - m));
    float lpb  = readlane0f(lp);
    B   = r + lp;
    b64 = b64 + lpb;
}

// ---------- forward half on raw-x g (stride GS): t = 0..127 ------------------
template<bool DPP>
__device__ __forceinline__ void ctc_fwd_g(const __half* gp, int lane, bool skip,
                                          int L, float& a_out, float& a64_out) {
    float xA[16], xB[16];
    #pragma unroll
    for (int k = 0; k < 16; ++k) xA[k] = __half2float(gp[(size_t)k * GS]);
    #pragma unroll
    for (int k = 0; k < 16; ++k) xB[k] = __half2float(gp[(size_t)(16 + k) * GS]);
    float a   = (lane == 0 || (lane == 1 && L > 0)) ? xA[0] : NEGV;
    float a64 = NEGV;
    #pragma unroll
    for (int k = 1; k < 16; ++k) fstep<DPP>(a, a64, xA[k], lane, skip);
    for (int c = 1; c <= 5; c += 2) {
        #pragma unroll
        for (int k = 0; k < 16; ++k) xA[k] = __half2float(gp[(size_t)((c+1)*16 + k) * GS]);
        #pragma unroll
        for (int k = 0; k < 16; ++k) fstep<DPP>(a, a64, xB[k], lane, skip);
        #pragma unroll
        for (int k = 0; k < 16; ++k) xB[k] = __half2float(gp[(size_t)((c+2)*16 + k) * GS]);
        #pragma unroll
        for (int k = 0; k < 16; ++k) fstep<DPP>(a, a64, xA[k], lane, skip);
    }
    #pragma unroll
    for (int k = 0; k < 16; ++k) fstep<DPP>(a, a64, xB[k], lane, skip);
    a_out = a; a64_out = a64;
}
// ---------- backward half on raw-x g: t = 255 (init) down to 128 -------------
template<bool DPP>
__device__ __forceinline__ void ctc_bwd_g(const __half* gp, int lane, bool skipT,
                                          int L, float& B_out, float& b64_out) {
    bool l63 = (lane == 63);
    float xA[16], xB[16];
    #pragma unroll
    for (int k = 0; k < 16; ++k) xA[k] = __half2float(gp[(size_t)(255 - k) * GS]);
    #pragma unroll
    for (int k = 0; k < 16; ++k) xB[k] = __half2float(gp[(size_t)(255 - 16 - k) * GS]);
    int twoL = 2 * L;
    float B   = ((lane == twoL) || (L > 0 && lane == twoL - 1)) ? xA[0] : NEGV;
    float b64 = (twoL == 64) ? readlane0f(xA[0]) : NEGV;
    #pragma unroll
    for (int k = 1; k < 16; ++k) bstep<DPP>(B, b64, xA[k], lane, skipT, l63);
    for (int c = 1; c <= 5; c += 2) {
        #pragma unroll
        for (int k = 0; k < 16; ++k) xA[k] = __half2float(gp[(size_t)(255 - (c+1)*16 - k) * GS]);
        #pragma unroll
        for (int k = 0; k < 16; ++k) bstep<DPP>(B, b64, xB[k], lane, skipT, l63);
        #pragma unroll
        for (int k = 0; k < 16; ++k) xB[k] = __half2float(gp[(size_t)(255 - (c+2)*16 - k) * GS]);
        #pragma unroll
        for (int k = 0; k < 16; ++k) bstep<DPP>(B, b64, xA[k], lane, skipT, l63);
    }
    #pragma unroll
    for (int k = 0; k < 16; ++k) bstep<DPP>(B, b64, xB[k], lane, skipT, l63);
    B_out = B; b64_out = b64;
}

// ---------------------------------------------------------------------------
// Kernel A (high-TLP): 8 rows per 256-thr block, half-wave per row.
// Coalesced float4 stream, DPP half-sum lse -> lsews[row]; 33 raw-x gathers
// from the L1-hot row -> fp16 g[row][34]. No LDS, no syncs.
// ---------------------------------------------------------------------------
__global__ void __launch_bounds__(256) lse_gather_kernel(const float* __restrict__ yp,
                                                         const int* __restrict__ yt,
                                                         __half* __restrict__ g,
                                                         float* __restrict__ lsews) {
    int tid  = threadIdx.x;
    int w    = tid >> 6;
    int lane = tid & 63;
    int li   = lane & 31;
    int row0 = blockIdx.x * 8 + w * 2;
    int row  = row0 + (lane >> 5);
    int b    = row0 >> 8;

    float ptst = halfsum_dpp((float)(lane + 1));
    bool sumok = __all(readlanef(ptst, 31) == 528.0f &&
                       readlanef(ptst, 63) == 1552.0f) != 0;

    float4 v = ((const float4*)(yp + (size_t)row0 * C_))[lane];
    #define E4(V) (__expf(fminf((V).x,80.f)) + __expf(fminf((V).y,80.f)) + \
                   __expf(fminf((V).z,80.f)) + __expf(fminf((V).w,80.f)))
    float e = E4(v);
    #undef E4
    float t = sumok ? halfsum_dpp(e) : halfsum_shfl(e);
    float s = (lane < 32) ? readlanef(t, 31) : readlanef(t, 63);
    float lse = __logf(s);
    if (li == 0) lsews[row] = lse;

    int cls = yt[b * LMAX + li];
    cls = min(max(cls, 0), C_ - 1);
    const float* rp = yp + (size_t)row * C_;   // L1-hot (just streamed)
    float xv = rp[cls];
    __half* gr = g + (size_t)row * GS;
    gr[1 + li] = __float2half_rn(xv);
    if (li == 0) gr[0] = __float2half_rn(rp[C_ - 1]);
}

// ---------------------------------------------------------------------------
// Kernel B: one block (3 waves) per example.
// wave0 = forward alpha to t=127; wave1 = backward beta to t=128;
// wave2 = S = sum of 256 lse's. Seam combine: loss = -(LSE_s(a+Bex) - S).
// ---------------------------------------------------------------------------
__global__ void __launch_bounds__(192) ctc_kernel(const __half* __restrict__ g,
                                                  const int* __restrict__ yt,
                                                  const float* __restrict__ lsews,
                                                  float* __restrict__ loss) {
    __shared__ float alphaS[65];
    __shared__ float BS[66];
    __shared__ float Ssh;
    int tid  = threadIdx.x;
    int w    = tid >> 6;
    int lane = tid & 63;
    int b    = blockIdx.x;
    const int* lab = yt + b * LMAX;

    int pr  = __builtin_amdgcn_update_dpp(-1, lane, 0x138, 0xF, 0xF, false);
    bool shrok = __all(pr == ((lane == 0) ? -1 : lane - 1)) != 0;
    int pl  = __builtin_amdgcn_update_dpp(-1, lane, 0x130, 0xF, 0xF, false);
    bool shlok = __all(pl == ((lane == 63) ? -1 : lane + 1)) != 0;

    if (w == 2) {
        float4 v = ((const float4*)(lsews + (size_t)b * T_))[lane];
        float s = v.x + v.y + v.z + v.w;
        #pragma unroll
        for (int off = 32; off; off >>= 1) s += __shfl_xor(s, off);
        if (lane == 0) Ssh = s;
    } else {
        int myl = (lane < LMAX) ? lab[lane] : 99;
        unsigned long long bal = __ballot(lane < LMAX && myl != 99);
        int L = __popcll(bal);
        int  j2  = lane >> 1;
        bool odd = (lane & 1) != 0;
        int  myslot = odd ? (1 + j2) : 0;
        const __half* gp = g + (size_t)b * T_ * GS + myslot;
        if (w == 0) {
            bool skip = odd && (lab[j2] != ((j2 > 0) ? lab[j2 - 1] : (C_ - 1)));
            float a, a64;
            if (shrok) ctc_fwd_g<true >(gp, lane, skip, L, a, a64);
            else       ctc_fwd_g<false>(gp, lane, skip, L, a, a64);
            alphaS[lane] = a;
            if (lane == 0) alphaS[64] = a64;
        } else {
            bool skipT = odd && (lane <= 61) && (lab[min(j2 + 1, 31)] != lab[j2]);
            float Bv, b64;
            if (shlok) ctc_bwd_g<true >(gp, lane, skipT, L, Bv, b64);
            else       ctc_bwd_g<false>(gp, lane, skipT, L, Bv, b64);
            BS[lane] = Bv;
            if (lane == 0) { BS[64] = b64; BS[65] = NEGV; }
        }
    }
    __syncthreads();
    if (w != 0) return;

    // seam: Bex[s] = LSE(B[s], B[s+1], skipT(s)?B[s+2]);  loss = -(LSE - S)
    int  j2  = lane >> 1;
    bool odd = (lane & 1) != 0;
    bool skipT = odd && (lane <= 61) && (lab[min(j2 + 1, 31)] != lab[j2]);
    float b0 = BS[lane];
    float b1 = BS[lane + 1];
    float b2 = skipT ? BS[lane + 2] : NEGV;
    float m  = fmaxf(fmaxf(b0, b1), b2);
    float bex = m + __logf(__expf(b0 - m) + __expf(b1 - m) + __expf(b2 - m));
    float v = alphaS[lane] + bex;
    if (lane == 0) v = laddexp(v, alphaS[64] + BS[64]);   // state-64 term
    float mm = v;
    #pragma unroll
    for (int off = 32; off; off >>= 1) mm = fmaxf(mm, __shfl_xor(mm, off));
    float se = __expf(v - mm);
    #pragma unroll
    for (int off = 32; off; off >>= 1) se += __shfl_xor(se, off);
    if (lane == 0) loss[b] = -(mm + __logf(se) - Ssh);
}

// ---------------------------------------------------------------------------
// mean of per-example losses -> d_out[0]
// ---------------------------------------------------------------------------
__global__ void __launch_bounds__(256) reduce_kernel(const float* __restrict__ loss,
                                                     float* __restrict__ out) {
    __shared__ float ps[4];
    int t = threadIdx.x;
    float4 v = ((const float4*)loss)[t];
    float s = v.x + v.y + v.z + v.w;
    #pragma unroll
    for (int off = 32; off; off >>= 1) s += __shfl_xor(s, off);
    if ((t & 63) == 0) ps[t >> 6] = s;
    __syncthreads();
    if (t == 0) out[0] = (ps[0] + ps[1] + ps[2] + ps[3]) * (1.0f / B_);
}

extern "C" void kernel_launch(void* const* d_in, const int* in_sizes, int n_in,
                              void* d_out, int out_size, void* d_ws, size_t ws_size,
                              hipStream_t stream) {
    const int*   yt  = (const int*)d_in[0];
    const float* yp  = (const float*)d_in[1];
    float*       out = (float*)d_out;

    size_t gbytes = (size_t)B_ * T_ * GS * sizeof(__half);      // 17,825,792
    __half* g     = (__half*)d_ws;
    float*  lsews = (float*)((char*)d_ws + gbytes);             // [B*T]
    float*  loss  = lsews + (size_t)B_ * T_;                    // [B]

    lse_gather_kernel<<<(B_ * T_) / 8, 256, 0, stream>>>(yp, yt, g, lsews);
    ctc_kernel<<<B_, 192, 0, stream>>>(g, yt, lsews, loss);
    reduce_kernel<<<1, 256, 0, stream>>>(loss, out);
}

// Round 14
// 71.500 us; speedup vs baseline: 1.0539x; 1.0539x over previous
//
#include <hip/hip_runtime.h>
#include <hip/hip_fp16.h>

#define B_    1024
#define T_    256
#define C_    128
#define LMAX  32
#define NEGV  -1e9f
#define STRH  274    // lph slot stride (halves): bank(slot)=9*slot%32, conflict-free
#define DUMP  33     // dump row for non-label classes

__device__ __forceinline__ float laddexp(float p, float q) {
    float m = fmaxf(p, q);
    float d = fabsf(p - q);
    return m + __logf(1.0f + __expf(-d));
}
__device__ __forceinline__ float dpp_shr1(float v) {  // dest[i]=src[i-1], lane0=NEGV
    int r = __builtin_amdgcn_update_dpp(__float_as_int(NEGV), __float_as_int(v),
                                        0x138, 0xF, 0xF, false);
    return __int_as_float(r);
}
__device__ __forceinline__ float dpp_shl1(float v) {  // dest[i]=src[i+1], lane63=NEGV
    int r = __builtin_amdgcn_update_dpp(__float_as_int(NEGV), __float_as_int(v),
                                        0x130, 0xF, 0xF, false);
    return __int_as_float(r);
}
template<int CTRL>
__device__ __forceinline__ float dpp_mov0(float v) {
    return __int_as_float(__builtin_amdgcn_update_dpp(0, __float_as_int(v),
                                                      CTRL, 0xF, 0xF, true));
}
__device__ __forceinline__ float readlanef(float v, int l) {
    return __int_as_float(__builtin_amdgcn_readlane(__float_as_int(v), l));
}
__device__ __forceinline__ float readlane0f(float v) {
    return __int_as_float(__builtin_amdgcn_readfirstlane(__float_as_int(v)));
}
// per-32-half sum: lane31 = sum(l0..31), lane63 = sum(l32..63)
__device__ __forceinline__ float halfsum_dpp(float v) {
    v += dpp_mov0<0x111>(v); v += dpp_mov0<0x112>(v);
    v += dpp_mov0<0x114>(v); v += dpp_mov0<0x118>(v);
    v += dpp_mov0<0x142>(v);   // row_bcast:15
    return v;
}
__device__ __forceinline__ float halfsum_shfl(float v) {
    #pragma unroll
    for (int off = 16; off; off >>= 1) v += __shfl_xor(v, off);
    return v;
}

// ---------- forward step (R12-verified): lane s holds alpha[s] ---------------
template<bool DPP>
__device__ __forceinline__ void fstep(float& a, float& a64, float lp,
                                      int lane, bool skip) {
    float am1, am2;
    if constexpr (DPP) {
        am1 = dpp_shr1(a);
        am2 = dpp_shr1(am1);
    } else {
        float s1 = __shfl_up(a, 1);
        float s2 = __shfl_up(a, 2);
        am1 = (lane < 1) ? NEGV : s1;
        am2 = (lane < 2) ? NEGV : s2;
    }
    float a63  = readlanef(a, 63);
    float am2e = skip ? am2 : NEGV;
    float m    = fmaxf(fmaxf(a, am1), am2e);
    float r    = m + __logf(__expf(a - m) + __expf(am1 - m) + __expf(am2e - m));
    float lpb  = readlane0f(lp);
    float m2   = fmaxf(a64, a63);
    float r64  = m2 + __logf(__expf(a64 - m2) + __expf(a63 - m2));
    a   = r + lp;
    a64 = r64 + lpb;
}
// ---------- backward step (R12-verified): lane s holds B[s] ------------------
template<bool DPP>
__device__ __forceinline__ void bstep(float& B, float& b64, float lp,
                                      int lane, bool skipT, bool l63) {
    float raw1, bs2;
    if constexpr (DPP) {
        raw1 = dpp_shl1(B);
        bs2  = dpp_shl1(raw1);
    } else {
        float s1 = __shfl_down(B, 1);
        float s2 = __shfl_down(B, 2);
        raw1 = (lane < 63) ? s1 : NEGV;
        bs2  = (lane < 62) ? s2 : NEGV;
    }
    float bs1  = l63 ? b64 : raw1;
    float bs2e = skipT ? bs2 : NEGV;
    float m    = fmaxf(fmaxf(B, bs1), bs2e);
    float r    = m + __logf(__expf(B - m) + __expf(bs1 - m) + __expf(bs2e - m));
    float lpb  = readlane0f(lp);
    B   = r + lp;
    b64 = b64 + lpb;
}

// ---------- forward half: t = 0..127 (stride-1 LDS row) ----------------------
template<bool DPP>
__device__ __forceinline__ void ctc_fwd_half(const __half* gb, int lane, bool skip,
                                             int L, float& a_out, float& a64_out) {
    float xA[16], xB[16];
    #pragma unroll
    for (int k = 0; k < 16; ++k) xA[k] = __half2float(gb[k]);
    #pragma unroll
    for (int k = 0; k < 16; ++k) xB[k] = __half2float(gb[16 + k]);
    float a   = (lane == 0 || (lane == 1 && L > 0)) ? xA[0] : NEGV;
    float a64 = NEGV;
    #pragma unroll
    for (int k = 1; k < 16; ++k) fstep<DPP>(a, a64, xA[k], lane, skip);
    for (int c = 1; c <= 5; c += 2) {
        #pragma unroll
        for (int k = 0; k < 16; ++k) xA[k] = __half2float(gb[(c + 1) * 16 + k]);
        #pragma unroll
        for (int k = 0; k < 16; ++k) fstep<DPP>(a, a64, xB[k], lane, skip);
        #pragma unroll
        for (int k = 0; k < 16; ++k) xB[k] = __half2float(gb[(c + 2) * 16 + k]);
        #pragma unroll
        for (int k = 0; k < 16; ++k) fstep<DPP>(a, a64, xA[k], lane, skip);
    }
    #pragma unroll
    for (int k = 0; k < 16; ++k) fstep<DPP>(a, a64, xB[k], lane, skip);
    a_out = a; a64_out = a64;
}
// ---------- backward half: t = 255 (init) down to 128 ------------------------
template<bool DPP>
__device__ __forceinline__ void ctc_bwd_half(const __half* gb, int lane, bool skipT,
                                             int L, float& B_out, float& b64_out) {
    bool l63 = (lane == 63);
    float xA[16], xB[16];
    #pragma unroll
    for (int k = 0; k < 16; ++k) xA[k] = __half2float(gb[255 - k]);
    #pragma unroll
    for (int k = 0; k < 16; ++k) xB[k] = __half2float(gb[255 - 16 - k]);
    int twoL = 2 * L;
    float B   = ((lane == twoL) || (L > 0 && lane == twoL - 1)) ? xA[0] : NEGV;
    float b64 = (twoL == 64) ? readlane0f(xA[0]) : NEGV;
    #pragma unroll
    for (int k = 1; k < 16; ++k) bstep<DPP>(B, b64, xA[k], lane, skipT, l63);
    for (int c = 1; c <= 5; c += 2) {
        #pragma unroll
        for (int k = 0; k < 16; ++k) xA[k] = __half2float(gb[255 - (c + 1) * 16 - k]);
        #pragma unroll
        for (int k = 0; k < 16; ++k) bstep<DPP>(B, b64, xB[k], lane, skipT, l63);
        #pragma unroll
        for (int k = 0; k < 16; ++k) xB[k] = __half2float(gb[255 - (c + 2) * 16 - k]);
        #pragma unroll
        for (int k = 0; k < 16; ++k) bstep<DPP>(B, b64, xA[k], lane, skipT, l63);
    }
    #pragma unroll
    for (int k = 0; k < 16; ++k) bstep<DPP>(B, b64, xB[k], lane, skipT, l63);
    B_out = B; b64_out = b64;
}

// ---------------------------------------------------------------------------
// Fused kernel: one block (512 thr, 8 waves) per example.
// Setup: class->owner-slot dedup map (LDS atomicMin, once per block); each
// lane gets 4 loop-invariant LDS write bases for its own 4 classes/row.
// Phase 1 (8 waves x 32 rows): fully-unrolled 4-deep float4 pipeline; per
// 2-row chunk: E4 exps + DPP half-sum + log + 4 subs/cvts + 4 ds_write_b16.
// No gather loads, no divergence, single cross-lane path (hoisted select).
// Phase 2: wave0 fwd alpha / wave1 bwd beta (R12-verified) + seam combine.
// ---------------------------------------------------------------------------
__global__ void __launch_bounds__(512) fused_kernel(const float* __restrict__ yp,
                                                    const int* __restrict__ yt,
                                                    float* __restrict__ loss) {
    __shared__ __half lph[34 * STRH + 320];   // +dump overflow pad
    __shared__ int    firstOwner[128];
    __shared__ int    ownerOfSlot[33];
    __shared__ float  alphaS[65];
    __shared__ float  BS[66];

    int tid  = threadIdx.x;
    int w    = tid >> 6;
    int lane = tid & 63;
    int li   = lane & 31;
    int b    = blockIdx.x;

    if (tid < 128) firstOwner[tid] = DUMP;

    // runtime DPP probes (wave-uniform; shfl fallback)
    int pr  = __builtin_amdgcn_update_dpp(-1, lane, 0x138, 0xF, 0xF, false);
    bool shrok = __all(pr == ((lane == 0) ? -1 : lane - 1)) != 0;
    int pl  = __builtin_amdgcn_update_dpp(-1, lane, 0x130, 0xF, 0xF, false);
    bool shlok = __all(pl == ((lane == 63) ? -1 : lane + 1)) != 0;
    float ptst = halfsum_dpp((float)(lane + 1));
    bool sumok = __all(readlanef(ptst, 31) == 528.0f &&
                       readlanef(ptst, 63) == 1552.0f) != 0;

    __syncthreads();
    if (tid < 33) {
        int c = (tid == 0) ? (C_ - 1)
                           : min(max(yt[b * LMAX + tid - 1], 0), C_ - 1);
        atomicMin(&firstOwner[c], tid);
    }
    __syncthreads();
    if (tid < 33) {
        int c = (tid == 0) ? (C_ - 1)
                           : min(max(yt[b * LMAX + tid - 1], 0), C_ - 1);
        ownerOfSlot[tid] = firstOwner[c];
    }
    // loop-invariant write bases: class 4*li+j -> owner slot row (or dump)
    int s0 = firstOwner[4 * li + 0];
    int s1 = firstOwner[4 * li + 1];
    int s2 = firstOwner[4 * li + 2];
    int s3 = firstOwner[4 * li + 3];
    int sa0 = (s0 == DUMP) ? (DUMP * STRH + lane) : s0 * STRH;
    int sa1 = (s1 == DUMP) ? (DUMP * STRH + lane) : s1 * STRH;
    int sa2 = (s2 == DUMP) ? (DUMP * STRH + lane) : s2 * STRH;
    int sa3 = (s3 == DUMP) ? (DUMP * STRH + lane) : s3 * STRH;

    // phase 1: wave w streams rows [w*32, w*32+32), 16 chunks of 2 rows
    const float4* srcQ = (const float4*)(yp + ((size_t)b * T_ + w * 32) * C_);
    int rbase = w * 32 + (lane >> 5);

    #define E4(V) (__expf(fminf((V).x,80.f)) + __expf(fminf((V).y,80.f)) + \
                   __expf(fminf((V).z,80.f)) + __expf(fminf((V).w,80.f)))
    #define WR(V, R) {                                                        \
        lph[sa0 + (R)] = __float2half_rn((V).x - lse);                        \
        lph[sa1 + (R)] = __float2half_rn((V).y - lse);                        \
        lph[sa2 + (R)] = __float2half_rn((V).z - lse);                        \
        lph[sa3 + (R)] = __float2half_rn((V).w - lse); }
    #define PROC_D(V, I) { float e = E4(V); float tt = halfsum_dpp(e);        \
        float ss = (lane < 32) ? readlanef(tt, 31) : readlanef(tt, 63);       \
        float lse = __logf(ss); WR(V, rbase + 2 * (I)) }
    #define PROC_S(V, I) { float e = E4(V); float ss = halfsum_shfl(e);       \
        float lse = __logf(ss); WR(V, rbase + 2 * (I)) }
    #define LOOP(PROC) {                                                      \
        float4 u0 = srcQ[lane], u1 = srcQ[64 + lane],                         \
               u2 = srcQ[128 + lane], u3 = srcQ[192 + lane];                  \
        _Pragma("unroll")                                                     \
        for (int ii = 0; ii < 4; ++ii) {                                      \
            float4 n0, n1, n2, n3;                                            \
            if (ii < 3) {                                                     \
                n0 = srcQ[(ii * 4 + 4) * 64 + lane];                          \
                n1 = srcQ[(ii * 4 + 5) * 64 + lane];                          \
                n2 = srcQ[(ii * 4 + 6) * 64 + lane];                          \
                n3 = srcQ[(ii * 4 + 7) * 64 + lane];                          \
            }                                                                 \
            PROC(u0, ii * 4 + 0); PROC(u1, ii * 4 + 1);                       \
            PROC(u2, ii * 4 + 2); PROC(u3, ii * 4 + 3);                       \
            if (ii < 3) { u0 = n0; u1 = n1; u2 = n2; u3 = n3; }               \
        } }

    if (sumok) LOOP(PROC_D)
    else       LOOP(PROC_S)
    #undef LOOP
    #undef PROC_D
    #undef PROC_S
    #undef WR
    #undef E4

    __syncthreads();

    // phase 2: wave 0 forward, wave 1 backward (others just hit the barrier)
    const int* lab = yt + b * LMAX;
    if (w < 2) {
        int myl = (lane < LMAX) ? lab[lane] : 99;
        unsigned long long bal = __ballot(lane < LMAX && myl != 99);
        int L = __popcll(bal);
        int  j2  = lane >> 1;
        bool odd = (lane & 1) != 0;
        int  myslot = odd ? (1 + j2) : 0;
        const __half* gbp = &lph[ownerOfSlot[myslot] * STRH];
        if (w == 0) {
            bool skip = odd && (lab[j2] != ((j2 > 0) ? lab[j2 - 1] : (C_ - 1)));
            float a, a64;
            if (shrok) ctc_fwd_half<true >(gbp, lane, skip, L, a, a64);
            else       ctc_fwd_half<false>(gbp, lane, skip, L, a, a64);
            alphaS[lane] = a;
            if (lane == 0) alphaS[64] = a64;
        } else {
            bool skipT = odd && (lane <= 61) && (lab[min(j2 + 1, 31)] != lab[j2]);
            float Bv, b64;
            if (shlok) ctc_bwd_half<true >(gbp, lane, skipT, L, Bv, b64);
            else       ctc_bwd_half<false>(gbp, lane, skipT, L, Bv, b64);
            BS[lane] = Bv;
            if (lane == 0) { BS[64] = b64; BS[65] = NEGV; }
        }
    }
    __syncthreads();
    if (w != 0) return;

    // seam (wave 0): Bex[s] = LSE(B[s], B[s+1], skipT(s)?B[s+2])
    {
        int  j2  = lane >> 1;
        bool odd = (lane & 1) != 0;
        bool skipT = odd && (lane <= 61) && (lab[min(j2 + 1, 31)] != lab[j2]);
        float b0 = BS[lane];
        float b1 = BS[lane + 1];
        float b2 = skipT ? BS[lane + 2] : NEGV;
        float m  = fmaxf(fmaxf(b0, b1), b2);
        float bex = m + __logf(__expf(b0 - m) + __expf(b1 - m) + __expf(b2 - m));
        float v = alphaS[lane] + bex;
        if (lane == 0) v = laddexp(v, alphaS[64] + BS[64]);   // state-64 term
        float mm = v;
        #pragma unroll
        for (int off = 32; off; off >>= 1) mm = fmaxf(mm, __shfl_xor(mm, off));
        float se = __expf(v - mm);
        #pragma unroll
        for (int off = 32; off; off >>= 1) se += __shfl_xor(se, off);
        if (lane == 0) loss[b] = -(mm + __logf(se));
    }
}

// ---------------------------------------------------------------------------
// mean of per-example losses -> d_out[0]
// ---------------------------------------------------------------------------
__global__ void __launch_bounds__(256) reduce_kernel(const float* __restrict__ loss,
                                                     float* __restrict__ out) {
    __shared__ float ps[4];
    int t = threadIdx.x;
    float4 v = ((const float4*)loss)[t];
    float s = v.x + v.y + v.z + v.w;
    #pragma unroll
    for (int off = 32; off; off >>= 1) s += __shfl_xor(s, off);
    if ((t & 63) == 0) ps[t >> 6] = s;
    __syncthreads();
    if (t == 0) out[0] = (ps[0] + ps[1] + ps[2] + ps[3]) * (1.0f / B_);
}

extern "C" void kernel_launch(void* const* d_in, const int* in_sizes, int n_in,
                              void* d_out, int out_size, void* d_ws, size_t ws_size,
                              hipStream_t stream) {
    const int*   yt  = (const int*)d_in[0];
    const float* yp  = (const float*)d_in[1];
    float*       out = (float*)d_out;
    float*       loss = (float*)d_ws;          // [B] floats

    fused_kernel<<<B_, 512, 0, stream>>>(yp, yt, loss);
    reduce_kernel<<<1, 256, 0, stream>>>(loss, out);
}

// Round 15
// 47.921 us; speedup vs baseline: 1.5724x; 1.4920x over previous
//
#include <hip/hip_runtime.h>
#include <hip/hip_fp16.h>

#define B_    1024
#define T_    256
#define C_    128
#define LMAX  32
#define DUMP  33
#define GSTR  8704   // per-example half stride: 34*256 (slots 0..32 used)

__device__ __forceinline__ float readlanef(float v, int l) {
    return __int_as_float(__builtin_amdgcn_readlane(__float_as_int(v), l));
}
__device__ __forceinline__ float readlane0f(float v) {
    return __int_as_float(__builtin_amdgcn_readfirstlane(__float_as_int(v)));
}
template<int CTRL>
__device__ __forceinline__ float dpp0f(float v) {   // bound_ctrl=1: shifted-in = 0
    return __int_as_float(__builtin_amdgcn_update_dpp(0, __float_as_int(v),
                                                      CTRL, 0xF, 0xF, true));
}
template<int CTRL>
__device__ __forceinline__ int dpp0i(int v) {
    return __builtin_amdgcn_update_dpp(0, v, CTRL, 0xF, 0xF, true);
}
// per-32-half sum: lane31 = sum(l0..31), lane63 = sum(l32..63)
__device__ __forceinline__ float halfsum_dpp(float v) {
    v += dpp0f<0x111>(v); v += dpp0f<0x112>(v);
    v += dpp0f<0x114>(v); v += dpp0f<0x118>(v);
    v += dpp0f<0x142>(v);
    return v;
}
__device__ __forceinline__ float halfsum_shfl(float v) {
    #pragma unroll
    for (int off = 16; off; off >>= 1) v += __shfl_xor(v, off);
    return v;
}
__device__ __forceinline__ float wavesum_dpp(float v) {
    v += dpp0f<0x111>(v); v += dpp0f<0x112>(v); v += dpp0f<0x114>(v);
    v += dpp0f<0x118>(v); v += dpp0f<0x142>(v); v += dpp0f<0x143>(v);
    return readlanef(v, 63);
}
__device__ __forceinline__ float wavemax_dpp(float v) {   // v >= 0
    v = fmaxf(v, dpp0f<0x111>(v)); v = fmaxf(v, dpp0f<0x112>(v));
    v = fmaxf(v, dpp0f<0x114>(v)); v = fmaxf(v, dpp0f<0x118>(v));
    v = fmaxf(v, dpp0f<0x142>(v)); v = fmaxf(v, dpp0f<0x143>(v));
    return readlanef(v, 63);
}

// ---------------- linear-domain steps (p = exp(x)/sumexp) --------------------
template<bool DPP>
__device__ __forceinline__ void fstepL(float& a, float& a64, float p,
                                       int lane, bool skip) {
    float am1, am2;
    if constexpr (DPP) { am1 = dpp0f<0x138>(a); am2 = dpp0f<0x138>(am1); }
    else {
        float s1 = __shfl_up(a, 1), s2 = __shfl_up(a, 2);
        am1 = (lane < 1) ? 0.f : s1;
        am2 = (lane < 2) ? 0.f : s2;
    }
    float a63 = readlanef(a, 63);
    float pb  = readlane0f(p);          // lane0 = slot0 = blank
    float sum = a + am1 + (skip ? am2 : 0.f);
    a64 = (a64 + a63) * pb;
    a   = sum * p;
}
template<bool DPP>
__device__ __forceinline__ void bstepL(float& B, float& b64, float p,
                                       int lane, bool skipT, bool l63) {
    float r1, b2;
    if constexpr (DPP) { r1 = dpp0f<0x130>(B); b2 = dpp0f<0x130>(r1); }
    else {
        float s1 = __shfl_down(B, 1), s2 = __shfl_down(B, 2);
        r1 = (lane < 63) ? s1 : 0.f;
        b2 = (lane < 62) ? s2 : 0.f;
    }
    float bs1 = l63 ? b64 : r1;
    float pb  = readlane0f(p);
    float sum = B + bs1 + (skipT ? b2 : 0.f);
    b64 = b64 * pb;
    B   = sum * p;
}
template<bool DPP>
__device__ __forceinline__ void rescaleL(float& x, float& x64, float& logZ) {
    float m;
    if constexpr (DPP) m = wavemax_dpp(x);
    else {
        float v = x;
        #pragma unroll
        for (int off = 32; off; off >>= 1) v = fmaxf(v, __shfl_xor(v, off));
        m = v;
    }
    m = fmaxf(fmaxf(m, x64), 1e-30f);
    float r = __builtin_amdgcn_rcpf(m);
    x *= r; x64 *= r; logZ += __logf(m);
}

#define LOAD16F(dst, base) { _Pragma("unroll")                                 \
    for (int j = 0; j < 8; ++j) {                                              \
        float2 f2 = __half22float2(*(const __half2*)(gp + (base) + 2 * j));    \
        dst[2 * j] = f2.x; dst[2 * j + 1] = f2.y; } }

// ---------- forward half: t = 0..127, rescale every 8 steps ------------------
template<bool DPP>
__device__ __forceinline__ void fwd_half(const __half* gp, int lane, bool skip,
                                         int L, float& a_o, float& a64_o, float& lz_o) {
    float xA[16], xB[16];
    LOAD16F(xA, 0); LOAD16F(xB, 16);
    float a = (lane == 0 || (lane == 1 && L > 0)) ? xA[0] : 0.f;
    float a64 = 0.f, logZ = 0.f;
    #pragma unroll
    for (int k = 1; k < 8; ++k) fstepL<DPP>(a, a64, xA[k], lane, skip);
    rescaleL<DPP>(a, a64, logZ);
    #pragma unroll
    for (int k = 8; k < 16; ++k) fstepL<DPP>(a, a64, xA[k], lane, skip);
    rescaleL<DPP>(a, a64, logZ);
    for (int c = 1; c <= 5; c += 2) {
        LOAD16F(xA, (c + 1) * 16);
        #pragma unroll
        for (int k = 0; k < 8; ++k) fstepL<DPP>(a, a64, xB[k], lane, skip);
        rescaleL<DPP>(a, a64, logZ);
        #pragma unroll
        for (int k = 8; k < 16; ++k) fstepL<DPP>(a, a64, xB[k], lane, skip);
        rescaleL<DPP>(a, a64, logZ);
        LOAD16F(xB, (c + 2) * 16);
        #pragma unroll
        for (int k = 0; k < 8; ++k) fstepL<DPP>(a, a64, xA[k], lane, skip);
        rescaleL<DPP>(a, a64, logZ);
        #pragma unroll
        for (int k = 8; k < 16; ++k) fstepL<DPP>(a, a64, xA[k], lane, skip);
        rescaleL<DPP>(a, a64, logZ);
    }
    #pragma unroll
    for (int k = 0; k < 8; ++k) fstepL<DPP>(a, a64, xB[k], lane, skip);
    rescaleL<DPP>(a, a64, logZ);
    #pragma unroll
    for (int k = 8; k < 16; ++k) fstepL<DPP>(a, a64, xB[k], lane, skip);
    rescaleL<DPP>(a, a64, logZ);
    a_o = a; a64_o = a64; lz_o = logZ;
}
// ---------- backward half: t = 255 (init) down to 128 ------------------------
template<bool DPP>
__device__ __forceinline__ void bwd_half(const __half* gp, int lane, bool skipT,
                                         int L, float& B_o, float& b64_o, float& lz_o) {
    bool l63 = (lane == 63);
    float xA[16], xB[16];
    LOAD16F(xA, 240); LOAD16F(xB, 224);
    int twoL = 2 * L;
    float p255 = xA[15];
    float B   = ((lane == twoL) || (L > 0 && lane == twoL - 1)) ? p255 : 0.f;
    float b64 = (twoL == 64) ? readlane0f(p255) : 0.f;
    float logZ = 0.f;
    #pragma unroll
    for (int k = 1; k < 8; ++k) bstepL<DPP>(B, b64, xA[15 - k], lane, skipT, l63);
    rescaleL<DPP>(B, b64, logZ);
    #pragma unroll
    for (int k = 8; k < 16; ++k) bstepL<DPP>(B, b64, xA[15 - k], lane, skipT, l63);
    rescaleL<DPP>(B, b64, logZ);
    for (int c = 1; c <= 5; c += 2) {
        LOAD16F(xA, 240 - (c + 1) * 16);
        #pragma unroll
        for (int k = 0; k < 8; ++k) bstepL<DPP>(B, b64, xB[15 - k], lane, skipT, l63);
        rescaleL<DPP>(B, b64, logZ);
        #pragma unroll
        for (int k = 8; k < 16; ++k) bstepL<DPP>(B, b64, xB[15 - k], lane, skipT, l63);
        rescaleL<DPP>(B, b64, logZ);
        LOAD16F(xB, 240 - (c + 2) * 16);
        #pragma unroll
        for (int k = 0; k < 8; ++k) bstepL<DPP>(B, b64, xA[15 - k], lane, skipT, l63);
        rescaleL<DPP>(B, b64, logZ);
        #pragma unroll
        for (int k = 8; k < 16; ++k) bstepL<DPP>(B, b64, xA[15 - k], lane, skipT, l63);
        rescaleL<DPP>(B, b64, logZ);
    }
    #pragma unroll
    for (int k = 0; k < 8; ++k) bstepL<DPP>(B, b64, xB[15 - k], lane, skipT, l63);
    rescaleL<DPP>(B, b64, logZ);
    #pragma unroll
    for (int k = 8; k < 16; ++k) bstepL<DPP>(B, b64, xB[15 - k], lane, skipT, l63);
    rescaleL<DPP>(B, b64, logZ);
    B_o = B; b64_o = b64; lz_o = logZ;
}

// ---------------------------------------------------------------------------
// K1: one block (512 thr, 8 waves) per example. Streams 256 rows (2 rows per
// wave-chunk, 4-deep float4 pipeline), computes p = exp(x)/sumexp per element
// and scatters the 33 label-slot p's (fp16) to g[b][slot][t]. No log at all.
// ---------------------------------------------------------------------------
__global__ void __launch_bounds__(512) prob_kernel(const float* __restrict__ yp,
                                                   const int* __restrict__ yt,
                                                   __half* __restrict__ g) {
    __shared__ int firstOwner[128];
    int tid  = threadIdx.x;
    int w    = tid >> 6;
    int lane = tid & 63;
    int li   = lane & 31;
    int b    = blockIdx.x;

    if (tid < 128) firstOwner[tid] = DUMP;
    float ptst = halfsum_dpp((float)(lane + 1));
    bool sumok = __all(readlanef(ptst, 31) == 528.0f &&
                       readlanef(ptst, 63) == 1552.0f) != 0;
    __syncthreads();
    if (tid < 33) {
        int c = (tid == 0) ? (C_ - 1)
                           : min(max(yt[b * LMAX + tid - 1], 0), C_ - 1);
        atomicMin(&firstOwner[c], tid);
    }
    __syncthreads();
    int s0 = firstOwner[4 * li + 0];
    int s1 = firstOwner[4 * li + 1];
    int s2 = firstOwner[4 * li + 2];
    int s3 = firstOwner[4 * li + 3];

    const float4* srcQ = (const float4*)(yp + ((size_t)b * T_ + w * 32) * C_);
    __half* gb_ = g + (size_t)b * GSTR;
    int rbase = w * 32 + (lane >> 5);

    #define PROC(V, I, HS) {                                                   \
        float e0 = __expf(fminf((V).x, 80.f)), e1 = __expf(fminf((V).y, 80.f));\
        float e2 = __expf(fminf((V).z, 80.f)), e3 = __expf(fminf((V).w, 80.f));\
        float tt = HS(e0 + e1 + e2 + e3);                                      \
        float ss = (lane < 32) ? readlanef(tt, 31) : readlanef(tt, 63);        \
        float rinv = __builtin_amdgcn_rcpf(ss);                                \
        int R = rbase + 2 * (I);                                               \
        if (s0 != DUMP) gb_[s0 * 256 + R] = __float2half_rn(e0 * rinv);        \
        if (s1 != DUMP) gb_[s1 * 256 + R] = __float2half_rn(e1 * rinv);        \
        if (s2 != DUMP) gb_[s2 * 256 + R] = __float2half_rn(e2 * rinv);        \
        if (s3 != DUMP) gb_[s3 * 256 + R] = __float2half_rn(e3 * rinv); }
    #define LOOP(HS) {                                                         \
        float4 u0 = srcQ[lane], u1 = srcQ[64 + lane],                          \
               u2 = srcQ[128 + lane], u3 = srcQ[192 + lane];                   \
        _Pragma("unroll")                                                      \
        for (int ii = 0; ii < 4; ++ii) {                                       \
            float4 n0, n1, n2, n3;                                             \
            if (ii < 3) {                                                      \
                n0 = srcQ[(ii * 4 + 4) * 64 + lane];                           \
                n1 = srcQ[(ii * 4 + 5) * 64 + lane];                           \
                n2 = srcQ[(ii * 4 + 6) * 64 + lane];                           \
                n3 = srcQ[(ii * 4 + 7) * 64 + lane];                           \
            }                                                                  \
            PROC(u0, ii * 4 + 0, HS); PROC(u1, ii * 4 + 1, HS);                \
            PROC(u2, ii * 4 + 2, HS); PROC(u3, ii * 4 + 3, HS);                \
            if (ii < 3) { u0 = n0; u1 = n1; u2 = n2; u3 = n3; }                \
        } }

    if (sumok) LOOP(halfsum_dpp)
    else       LOOP(halfsum_shfl)
    #undef LOOP
    #undef PROC
}

// ---------------------------------------------------------------------------
// K2: one block (128 thr, 2 waves) per example. wave0 = forward alpha (linear,
// rescaled), wave1 = backward beta. Seam: loss = -(log(sum a*Bex + a64*B64)
// + logZa + logZb).
// ---------------------------------------------------------------------------
__global__ void __launch_bounds__(128) ctc_kernel(const __half* __restrict__ g,
                                                  const int* __restrict__ yt,
                                                  float* __restrict__ loss) {
    __shared__ int   firstOwner[128];
    __shared__ int   owner[33];
    __shared__ float alphaS[65], BS[66];
    __shared__ float lzA, lzB;
    int tid  = threadIdx.x;
    int w    = tid >> 6;
    int lane = tid & 63;
    int b    = blockIdx.x;
    const int* lab = yt + b * LMAX;

    if (tid < 128) firstOwner[tid] = DUMP;
    int pr = dpp0i<0x138>(lane + 1);
    bool shrok = __all(pr == ((lane == 0) ? 0 : lane)) != 0;
    int pl = dpp0i<0x130>(lane + 1);
    bool shlok = __all(pl == ((lane == 63) ? 0 : lane + 2)) != 0;
    float fs = wavesum_dpp((float)(lane + 1));
    bool fullok = __all(fs == 2080.0f) != 0;
    __syncthreads();
    if (tid < 33) {
        int c = (tid == 0) ? (C_ - 1)
                           : min(max(lab[tid - 1], 0), C_ - 1);
        atomicMin(&firstOwner[c], tid);
    }
    __syncthreads();
    if (tid < 33) {
        int c = (tid == 0) ? (C_ - 1)
                           : min(max(lab[tid - 1], 0), C_ - 1);
        owner[tid] = firstOwner[c];
    }
    __syncthreads();

    int myl = (lane < LMAX) ? lab[lane] : 99;
    unsigned long long bal = __ballot(lane < LMAX && myl != 99);
    int L = __popcll(bal);
    int  j2  = lane >> 1;
    bool odd = (lane & 1) != 0;
    int  myslot = odd ? (1 + j2) : 0;
    const __half* gp = g + (size_t)b * GSTR + (size_t)owner[myslot] * 256;

    if (w == 0) {
        bool skip = odd && (lab[j2] != ((j2 > 0) ? lab[j2 - 1] : (C_ - 1)));
        float a, a64, lz;
        if (shrok && fullok) fwd_half<true >(gp, lane, skip, L, a, a64, lz);
        else                 fwd_half<false>(gp, lane, skip, L, a, a64, lz);
        alphaS[lane] = a;
        if (lane == 0) { alphaS[64] = a64; lzA = lz; }
    } else {
        bool skipT = odd && (lane <= 61) && (lab[min(j2 + 1, 31)] != lab[j2]);
        float Bv, b64, lz;
        if (shlok && fullok) bwd_half<true >(gp, lane, skipT, L, Bv, b64, lz);
        else                 bwd_half<false>(gp, lane, skipT, L, Bv, b64, lz);
        BS[lane] = Bv;
        if (lane == 0) { BS[64] = b64; BS[65] = 0.f; lzB = lz; }
    }
    __syncthreads();
    if (w != 0) return;

    bool skipT = odd && (lane <= 61) && (lab[min(j2 + 1, 31)] != lab[j2]);
    float bex = BS[lane] + BS[lane + 1] + (skipT ? BS[lane + 2] : 0.f);
    float contrib = alphaS[lane] * bex;
    if (lane == 0) contrib += alphaS[64] * BS[64];
    #pragma unroll
    for (int off = 32; off; off >>= 1) contrib += __shfl_xor(contrib, off);
    if (lane == 0) loss[b] = -(__logf(fmaxf(contrib, 1e-37f)) + lzA + lzB);
}

// ---------------------------------------------------------------------------
// K3: mean of per-example losses -> d_out[0]
// ---------------------------------------------------------------------------
__global__ void __launch_bounds__(256) reduce_kernel(const float* __restrict__ loss,
                                                     float* __restrict__ out) {
    __shared__ float ps[4];
    int t = threadIdx.x;
    float4 v = ((const float4*)loss)[t];
    float s = v.x + v.y + v.z + v.w;
    #pragma unroll
    for (int off = 32; off; off >>= 1) s += __shfl_xor(s, off);
    if ((t & 63) == 0) ps[t >> 6] = s;
    __syncthreads();
    if (t == 0) out[0] = (ps[0] + ps[1] + ps[2] + ps[3]) * (1.0f / B_);
}

extern "C" void kernel_launch(void* const* d_in, const int* in_sizes, int n_in,
                              void* d_out, int out_size, void* d_ws, size_t ws_size,
                              hipStream_t stream) {
    const int*   yt  = (const int*)d_in[0];
    const float* yp  = (const float*)d_in[1];
    float*       out = (float*)d_out;

    size_t gbytes = (size_t)B_ * GSTR * sizeof(__half);   // 17,825,792
    __half* g    = (__half*)d_ws;
    float*  loss = (float*)((char*)d_ws + gbytes);        // [B]

    prob_kernel<<<B_, 512, 0, stream>>>(yp, yt, g);
    ctc_kernel<<<B_, 128, 0, stream>>>(g, yt, loss);
    reduce_kernel<<<1, 256, 0, stream>>>(loss, out);
}

// Round 16
// 45.408 us; speedup vs baseline: 1.6594x; 1.0553x over previous
//
#include <hip/hip_runtime.h>
#include <hip/hip_fp16.h>

#define B_    1024
#define T_    256
#define C_    128
#define LMAX  32
#define DUMP  33
#define RSTR  36                 // g row stride in halves: [b][t][36]
#define GSTR  (T_ * RSTR)        // per-example half stride = 9216

__device__ __forceinline__ float readlanef(float v, int l) {
    return __int_as_float(__builtin_amdgcn_readlane(__float_as_int(v), l));
}
__device__ __forceinline__ float readlane0f(float v) {
    return __int_as_float(__builtin_amdgcn_readfirstlane(__float_as_int(v)));
}
template<int CTRL>
__device__ __forceinline__ float dpp0f(float v) {   // bound_ctrl=1: shifted-in = 0
    return __int_as_float(__builtin_amdgcn_update_dpp(0, __float_as_int(v),
                                                      CTRL, 0xF, 0xF, true));
}
template<int CTRL>
__device__ __forceinline__ int dpp0i(int v) {
    return __builtin_amdgcn_update_dpp(0, v, CTRL, 0xF, 0xF, true);
}
// per-32-half sum: lane31 = sum(l0..31), lane63 = sum(l32..63)
__device__ __forceinline__ float halfsum_dpp(float v) {
    v += dpp0f<0x111>(v); v += dpp0f<0x112>(v);
    v += dpp0f<0x114>(v); v += dpp0f<0x118>(v);
    v += dpp0f<0x142>(v);
    return v;
}
__device__ __forceinline__ float halfsum_shfl(float v) {
    #pragma unroll
    for (int off = 16; off; off >>= 1) v += __shfl_xor(v, off);
    return v;
}
__device__ __forceinline__ float wavesum_dpp(float v) {
    v += dpp0f<0x111>(v); v += dpp0f<0x112>(v); v += dpp0f<0x114>(v);
    v += dpp0f<0x118>(v); v += dpp0f<0x142>(v); v += dpp0f<0x143>(v);
    return readlanef(v, 63);
}
__device__ __forceinline__ float wavemax_dpp(float v) {   // v >= 0
    v = fmaxf(v, dpp0f<0x111>(v)); v = fmaxf(v, dpp0f<0x112>(v));
    v = fmaxf(v, dpp0f<0x114>(v)); v = fmaxf(v, dpp0f<0x118>(v));
    v = fmaxf(v, dpp0f<0x142>(v)); v = fmaxf(v, dpp0f<0x143>(v));
    return readlanef(v, 63);
}

// ---------------- linear-domain steps (p = exp(x)/sumexp) --------------------
template<bool DPP>
__device__ __forceinline__ void fstepL(float& a, float& a64, float p,
                                       int lane, bool skip) {
    float am1, am2;
    if constexpr (DPP) { am1 = dpp0f<0x138>(a); am2 = dpp0f<0x138>(am1); }
    else {
        float s1 = __shfl_up(a, 1), s2 = __shfl_up(a, 2);
        am1 = (lane < 1) ? 0.f : s1;
        am2 = (lane < 2) ? 0.f : s2;
    }
    float a63 = readlanef(a, 63);
    float pb  = readlane0f(p);          // lane0 = slot0 = blank
    float sum = a + am1 + (skip ? am2 : 0.f);
    a64 = (a64 + a63) * pb;
    a   = sum * p;
}
template<bool DPP>
__device__ __forceinline__ void bstepL(float& B, float& b64, float p,
                                       int lane, bool skipT, bool l63) {
    float r1, b2;
    if constexpr (DPP) { r1 = dpp0f<0x130>(B); b2 = dpp0f<0x130>(r1); }
    else {
        float s1 = __shfl_down(B, 1), s2 = __shfl_down(B, 2);
        r1 = (lane < 63) ? s1 : 0.f;
        b2 = (lane < 62) ? s2 : 0.f;
    }
    float bs1 = l63 ? b64 : r1;
    float pb  = readlane0f(p);
    float sum = B + bs1 + (skipT ? b2 : 0.f);
    b64 = b64 * pb;
    B   = sum * p;
}
template<bool DPP>
__device__ __forceinline__ void rescaleL(float& x, float& x64, float& logZ) {
    float m;
    if constexpr (DPP) m = wavemax_dpp(x);
    else {
        float v = x;
        #pragma unroll
        for (int off = 32; off; off >>= 1) v = fmaxf(v, __shfl_xor(v, off));
        m = v;
    }
    m = fmaxf(fmaxf(m, x64), 1e-30f);
    float r = __builtin_amdgcn_rcpf(m);
    x *= r; x64 *= r; logZ += __logf(m);
}

// load 16 consecutive-t probabilities for this lane's slot ([t][36] layout)
#define LOAD16F(dst, tb) { _Pragma("unroll")                                   \
    for (int j = 0; j < 16; ++j)                                               \
        dst[j] = __half2float(gp[(size_t)((tb) + j) * RSTR]); }

// ---------- forward half: t = 0..127, rescale every 8 steps ------------------
template<bool DPP>
__device__ __forceinline__ void fwd_half(const __half* gp, int lane, bool skip,
                                         int L, float& a_o, float& a64_o, float& lz_o) {
    float xA[16], xB[16];
    LOAD16F(xA, 0); LOAD16F(xB, 16);
    float a = (lane == 0 || (lane == 1 && L > 0)) ? xA[0] : 0.f;
    float a64 = 0.f, logZ = 0.f;
    #pragma unroll
    for (int k = 1; k < 8; ++k) fstepL<DPP>(a, a64, xA[k], lane, skip);
    rescaleL<DPP>(a, a64, logZ);
    #pragma unroll
    for (int k = 8; k < 16; ++k) fstepL<DPP>(a, a64, xA[k], lane, skip);
    rescaleL<DPP>(a, a64, logZ);
    for (int c = 1; c <= 5; c += 2) {
        LOAD16F(xA, (c + 1) * 16);
        #pragma unroll
        for (int k = 0; k < 8; ++k) fstepL<DPP>(a, a64, xB[k], lane, skip);
        rescaleL<DPP>(a, a64, logZ);
        #pragma unroll
        for (int k = 8; k < 16; ++k) fstepL<DPP>(a, a64, xB[k], lane, skip);
        rescaleL<DPP>(a, a64, logZ);
        LOAD16F(xB, (c + 2) * 16);
        #pragma unroll
        for (int k = 0; k < 8; ++k) fstepL<DPP>(a, a64, xA[k], lane, skip);
        rescaleL<DPP>(a, a64, logZ);
        #pragma unroll
        for (int k = 8; k < 16; ++k) fstepL<DPP>(a, a64, xA[k], lane, skip);
        rescaleL<DPP>(a, a64, logZ);
    }
    #pragma unroll
    for (int k = 0; k < 8; ++k) fstepL<DPP>(a, a64, xB[k], lane, skip);
    rescaleL<DPP>(a, a64, logZ);
    #pragma unroll
    for (int k = 8; k < 16; ++k) fstepL<DPP>(a, a64, xB[k], lane, skip);
    rescaleL<DPP>(a, a64, logZ);
    a_o = a; a64_o = a64; lz_o = logZ;
}
// ---------- backward half: t = 255 (init) down to 128 ------------------------
template<bool DPP>
__device__ __forceinline__ void bwd_half(const __half* gp, int lane, bool skipT,
                                         int L, float& B_o, float& b64_o, float& lz_o) {
    bool l63 = (lane == 63);
    float xA[16], xB[16];
    LOAD16F(xA, 240); LOAD16F(xB, 224);
    int twoL = 2 * L;
    float p255 = xA[15];
    float B   = ((lane == twoL) || (L > 0 && lane == twoL - 1)) ? p255 : 0.f;
    float b64 = (twoL == 64) ? readlane0f(p255) : 0.f;
    float logZ = 0.f;
    #pragma unroll
    for (int k = 1; k < 8; ++k) bstepL<DPP>(B, b64, xA[15 - k], lane, skipT, l63);
    rescaleL<DPP>(B, b64, logZ);
    #pragma unroll
    for (int k = 8; k < 16; ++k) bstepL<DPP>(B, b64, xA[15 - k], lane, skipT, l63);
    rescaleL<DPP>(B, b64, logZ);
    for (int c = 1; c <= 5; c += 2) {
        LOAD16F(xA, 240 - (c + 1) * 16);
        #pragma unroll
        for (int k = 0; k < 8; ++k) bstepL<DPP>(B, b64, xB[15 - k], lane, skipT, l63);
        rescaleL<DPP>(B, b64, logZ);
        #pragma unroll
        for (int k = 8; k < 16; ++k) bstepL<DPP>(B, b64, xB[15 - k], lane, skipT, l63);
        rescaleL<DPP>(B, b64, logZ);
        LOAD16F(xB, 240 - (c + 2) * 16);
        #pragma unroll
        for (int k = 0; k < 8; ++k) bstepL<DPP>(B, b64, xA[15 - k], lane, skipT, l63);
        rescaleL<DPP>(B, b64, logZ);
        #pragma unroll
        for (int k = 8; k < 16; ++k) bstepL<DPP>(B, b64, xA[15 - k], lane, skipT, l63);
        rescaleL<DPP>(B, b64, logZ);
    }
    #pragma unroll
    for (int k = 0; k < 8; ++k) bstepL<DPP>(B, b64, xB[15 - k], lane, skipT, l63);
    rescaleL<DPP>(B, b64, logZ);
    #pragma unroll
    for (int k = 8; k < 16; ++k) bstepL<DPP>(B, b64, xB[15 - k], lane, skipT, l63);
    rescaleL<DPP>(B, b64, logZ);
    B_o = B; b64_o = b64; lz_o = logZ;
}

// ---------------------------------------------------------------------------
// K1: one block (512 thr, 8 waves) per example. Streams 256 rows, computes
// p = exp(x)/sumexp and scatters the 33 label-slot p's (fp16) to g[b][t][36]
// (72 B contiguous window per t -> 1-2 lines per chunk-column).
// ---------------------------------------------------------------------------
__global__ void __launch_bounds__(512) prob_kernel(const float* __restrict__ yp,
                                                   const int* __restrict__ yt,
                                                   __half* __restrict__ g) {
    __shared__ int firstOwner[128];
    int tid  = threadIdx.x;
    int w    = tid >> 6;
    int lane = tid & 63;
    int li   = lane & 31;
    int b    = blockIdx.x;

    if (tid < 128) firstOwner[tid] = DUMP;
    float ptst = halfsum_dpp((float)(lane + 1));
    bool sumok = __all(readlanef(ptst, 31) == 528.0f &&
                       readlanef(ptst, 63) == 1552.0f) != 0;
    __syncthreads();
    if (tid < 33) {
        int c = (tid == 0) ? (C_ - 1)
                           : min(max(yt[b * LMAX + tid - 1], 0), C_ - 1);
        atomicMin(&firstOwner[c], tid);
    }
    __syncthreads();
    int s0 = firstOwner[4 * li + 0];
    int s1 = firstOwner[4 * li + 1];
    int s2 = firstOwner[4 * li + 2];
    int s3 = firstOwner[4 * li + 3];

    const float4* srcQ = (const float4*)(yp + ((size_t)b * T_ + w * 32) * C_);
    __half* gb_ = g + (size_t)b * GSTR;
    int rbase = w * 32 + (lane >> 5);

    #define PROC(V, I, HS) {                                                   \
        float e0 = __expf(fminf((V).x, 80.f)), e1 = __expf(fminf((V).y, 80.f));\
        float e2 = __expf(fminf((V).z, 80.f)), e3 = __expf(fminf((V).w, 80.f));\
        float tt = HS(e0 + e1 + e2 + e3);                                      \
        float ss = (lane < 32) ? readlanef(tt, 31) : readlanef(tt, 63);        \
        float rinv = __builtin_amdgcn_rcpf(ss);                                \
        size_t R = (size_t)(rbase + 2 * (I)) * RSTR;                           \
        if (s0 != DUMP) gb_[R + s0] = __float2half_rn(e0 * rinv);              \
        if (s1 != DUMP) gb_[R + s1] = __float2half_rn(e1 * rinv);              \
        if (s2 != DUMP) gb_[R + s2] = __float2half_rn(e2 * rinv);              \
        if (s3 != DUMP) gb_[R + s3] = __float2half_rn(e3 * rinv); }
    #define LOOP(HS) {                                                         \
        float4 u0 = srcQ[lane], u1 = srcQ[64 + lane],                          \
               u2 = srcQ[128 + lane], u3 = srcQ[192 + lane];                   \
        _Pragma("unroll")                                                      \
        for (int ii = 0; ii < 4; ++ii) {                                       \
            float4 n0, n1, n2, n3;                                             \
            if (ii < 3) {                                                      \
                n0 = srcQ[(ii * 4 + 4) * 64 + lane];                           \
                n1 = srcQ[(ii * 4 + 5) * 64 + lane];                           \
                n2 = srcQ[(ii * 4 + 6) * 64 + lane];                           \
                n3 = srcQ[(ii * 4 + 7) * 64 + lane];                           \
            }                                                                  \
            PROC(u0, ii * 4 + 0, HS); PROC(u1, ii * 4 + 1, HS);                \
            PROC(u2, ii * 4 + 2, HS); PROC(u3, ii * 4 + 3, HS);                \
            if (ii < 3) { u0 = n0; u1 = n1; u2 = n2; u3 = n3; }                \
        } }

    if (sumok) LOOP(halfsum_dpp)
    else       LOOP(halfsum_shfl)
    #undef LOOP
    #undef PROC
}

// ---------------------------------------------------------------------------
// K2: one block (128 thr, 2 waves) per example. wave0 = forward alpha (linear,
// rescaled), wave1 = backward beta. At each step all 64 lanes read within one
// 72 B window of g[b][t][36]. Seam: loss = -(log(sum a*Bex + a64*B64)
// + logZa + logZb).
// ---------------------------------------------------------------------------
__global__ void __launch_bounds__(128) ctc_kernel(const __half* __restrict__ g,
                                                  const int* __restrict__ yt,
                                                  float* __restrict__ loss) {
    __shared__ int   firstOwner[128];
    __shared__ int   owner[33];
    __shared__ float alphaS[65], BS[66];
    __shared__ float lzA, lzB;
    int tid  = threadIdx.x;
    int w    = tid >> 6;
    int lane = tid & 63;
    int b    = blockIdx.x;
    const int* lab = yt + b * LMAX;

    if (tid < 128) firstOwner[tid] = DUMP;
    int pr = dpp0i<0x138>(lane + 1);
    bool shrok = __all(pr == ((lane == 0) ? 0 : lane)) != 0;
    int pl = dpp0i<0x130>(lane + 1);
    bool shlok = __all(pl == ((lane == 63) ? 0 : lane + 2)) != 0;
    float fs = wavesum_dpp((float)(lane + 1));
    bool fullok = __all(fs == 2080.0f) != 0;
    __syncthreads();
    if (tid < 33) {
        int c = (tid == 0) ? (C_ - 1)
                           : min(max(lab[tid - 1], 0), C_ - 1);
        atomicMin(&firstOwner[c], tid);
    }
    __syncthreads();
    if (tid < 33) {
        int c = (tid == 0) ? (C_ - 1)
                           : min(max(lab[tid - 1], 0), C_ - 1);
        owner[tid] = firstOwner[c];
    }
    __syncthreads();

    int myl = (lane < LMAX) ? lab[lane] : 99;
    unsigned long long bal = __ballot(lane < LMAX && myl != 99);
    int L = __popcll(bal);
    int  j2  = lane >> 1;
    bool odd = (lane & 1) != 0;
    int  myslot = odd ? (1 + j2) : 0;
    const __half* gp = g + (size_t)b * GSTR + owner[myslot];

    if (w == 0) {
        bool skip = odd && (lab[j2] != ((j2 > 0) ? lab[j2 - 1] : (C_ - 1)));
        float a, a64, lz;
        if (shrok && fullok) fwd_half<true >(gp, lane, skip, L, a, a64, lz);
        else                 fwd_half<false>(gp, lane, skip, L, a, a64, lz);
        alphaS[lane] = a;
        if (lane == 0) { alphaS[64] = a64; lzA = lz; }
    } else {
        bool skipT = odd && (lane <= 61) && (lab[min(j2 + 1, 31)] != lab[j2]);
        float Bv, b64, lz;
        if (shlok && fullok) bwd_half<true >(gp, lane, skipT, L, Bv, b64, lz);
        else                 bwd_half<false>(gp, lane, skipT, L, Bv, b64, lz);
        BS[lane] = Bv;
        if (lane == 0) { BS[64] = b64; BS[65] = 0.f; lzB = lz; }
    }
    __syncthreads();
    if (w != 0) return;

    bool skipT = odd && (lane <= 61) && (lab[min(j2 + 1, 31)] != lab[j2]);
    float bex = BS[lane] + BS[lane + 1] + (skipT ? BS[lane + 2] : 0.f);
    float contrib = alphaS[lane] * bex;
    if (lane == 0) contrib += alphaS[64] * BS[64];
    #pragma unroll
    for (int off = 32; off; off >>= 1) contrib += __shfl_xor(contrib, off);
    if (lane == 0) loss[b] = -(__logf(fmaxf(contrib, 1e-37f)) + lzA + lzB);
}

// ---------------------------------------------------------------------------
// K3: mean of per-example losses -> d_out[0]
// ---------------------------------------------------------------------------
__global__ void __launch_bounds__(256) reduce_kernel(const float* __restrict__ loss,
                                                     float* __restrict__ out) {
    __shared__ float ps[4];
    int t = threadIdx.x;
    float4 v = ((const float4*)loss)[t];
    float s = v.x + v.y + v.z + v.w;
    #pragma unroll
    for (int off = 32; off; off >>= 1) s += __shfl_xor(s, off);
    if ((t & 63) == 0) ps[t >> 6] = s;
    __syncthreads();
    if (t == 0) out[0] = (ps[0] + ps[1] + ps[2] + ps[3]) * (1.0f / B_);
}

extern "C" void kernel_launch(void* const* d_in, const int* in_sizes, int n_in,
                              void* d_out, int out_size, void* d_ws, size_t ws_size,
                              hipStream_t stream) {
    const int*   yt  = (const int*)d_in[0];
    const float* yp  = (const float*)d_in[1];
    float*       out = (float*)d_out;

    size_t gbytes = (size_t)B_ * GSTR * sizeof(__half);   // 18,874,368
    __half* g    = (__half*)d_ws;
    float*  loss = (float*)((char*)d_ws + gbytes);        // [B]

    prob_kernel<<<B_, 512, 0, stream>>>(yp, yt, g);
    ctc_kernel<<<B_, 128, 0, stream>>>(g, yt, loss);
    reduce_kernel<<<1, 256, 0, stream>>>(loss, out);
}

// Round 17
// 42.041 us; speedup vs baseline: 1.7923x; 1.0801x over previous
//
#include <hip/hip_runtime.h>
#include <hip/hip_fp16.h>

#define B_    1024
#define T_    256
#define C_    128
#define LMAX  32
#define DUMP  33
#define RSTR  36                 // lph row stride in halves: [t][36]

__device__ __forceinline__ float readlanef(float v, int l) {
    return __int_as_float(__builtin_amdgcn_readlane(__float_as_int(v), l));
}
__device__ __forceinline__ float readlane0f(float v) {
    return __int_as_float(__builtin_amdgcn_readfirstlane(__float_as_int(v)));
}
template<int CTRL>
__device__ __forceinline__ float dpp0f(float v) {   // bound_ctrl=1: shifted-in = 0
    return __int_as_float(__builtin_amdgcn_update_dpp(0, __float_as_int(v),
                                                      CTRL, 0xF, 0xF, true));
}
template<int CTRL>
__device__ __forceinline__ int dpp0i(int v) {
    return __builtin_amdgcn_update_dpp(0, v, CTRL, 0xF, 0xF, true);
}
// per-32-half sum: lane31 = sum(l0..31), lane63 = sum(l32..63)
__device__ __forceinline__ float halfsum_dpp(float v) {
    v += dpp0f<0x111>(v); v += dpp0f<0x112>(v);
    v += dpp0f<0x114>(v); v += dpp0f<0x118>(v);
    v += dpp0f<0x142>(v);
    return v;
}
__device__ __forceinline__ float halfsum_shfl(float v) {
    #pragma unroll
    for (int off = 16; off; off >>= 1) v += __shfl_xor(v, off);
    return v;
}
__device__ __forceinline__ float wavesum_dpp(float v) {
    v += dpp0f<0x111>(v); v += dpp0f<0x112>(v); v += dpp0f<0x114>(v);
    v += dpp0f<0x118>(v); v += dpp0f<0x142>(v); v += dpp0f<0x143>(v);
    return readlanef(v, 63);
}
__device__ __forceinline__ float wavemax_dpp(float v) {   // v >= 0
    v = fmaxf(v, dpp0f<0x111>(v)); v = fmaxf(v, dpp0f<0x112>(v));
    v = fmaxf(v, dpp0f<0x114>(v)); v = fmaxf(v, dpp0f<0x118>(v));
    v = fmaxf(v, dpp0f<0x142>(v)); v = fmaxf(v, dpp0f<0x143>(v));
    return readlanef(v, 63);
}

// ---------------- linear-domain steps (p = exp(x)/sumexp) --------------------
template<bool DPP>
__device__ __forceinline__ void fstepL(float& a, float& a64, float p,
                                       int lane, bool skip) {
    float am1, am2;
    if constexpr (DPP) { am1 = dpp0f<0x138>(a); am2 = dpp0f<0x138>(am1); }
    else {
        float s1 = __shfl_up(a, 1), s2 = __shfl_up(a, 2);
        am1 = (lane < 1) ? 0.f : s1;
        am2 = (lane < 2) ? 0.f : s2;
    }
    float a63 = readlanef(a, 63);
    float pb  = readlane0f(p);          // lane0 = slot0 = blank
    float sum = a + am1 + (skip ? am2 : 0.f);
    a64 = (a64 + a63) * pb;
    a   = sum * p;
}
template<bool DPP>
__device__ __forceinline__ void bstepL(float& B, float& b64, float p,
                                       int lane, bool skipT, bool l63) {
    float r1, b2;
    if constexpr (DPP) { r1 = dpp0f<0x130>(B); b2 = dpp0f<0x130>(r1); }
    else {
        float s1 = __shfl_down(B, 1), s2 = __shfl_down(B, 2);
        r1 = (lane < 63) ? s1 : 0.f;
        b2 = (lane < 62) ? s2 : 0.f;
    }
    float bs1 = l63 ? b64 : r1;
    float pb  = readlane0f(p);
    float sum = B + bs1 + (skipT ? b2 : 0.f);
    b64 = b64 * pb;
    B   = sum * p;
}
template<bool DPP>
__device__ __forceinline__ void rescaleL(float& x, float& x64, float& logZ) {
    float m;
    if constexpr (DPP) m = wavemax_dpp(x);
    else {
        float v = x;
        #pragma unroll
        for (int off = 32; off; off >>= 1) v = fmaxf(v, __shfl_xor(v, off));
        m = v;
    }
    m = fmaxf(fmaxf(m, x64), 1e-30f);
    float r = __builtin_amdgcn_rcpf(m);
    x *= r; x64 *= r; logZ += __logf(m);
}

// load 16 consecutive-t probabilities for this lane's slot ([t][36] layout)
#define LOAD16F(dst, tb) { _Pragma("unroll")                                   \
    for (int j = 0; j < 16; ++j)                                               \
        dst[j] = __half2float(gp[(tb + j) * RSTR]); }

// ---------- forward half: t = 0..127, rescale every 8 steps ------------------
template<bool DPP>
__device__ __forceinline__ void fwd_half(const __half* gp, int lane, bool skip,
                                         int L, float& a_o, float& a64_o, float& lz_o) {
    float xA[16], xB[16];
    LOAD16F(xA, 0); LOAD16F(xB, 16);
    float a = (lane == 0 || (lane == 1 && L > 0)) ? xA[0] : 0.f;
    float a64 = 0.f, logZ = 0.f;
    #pragma unroll
    for (int k = 1; k < 8; ++k) fstepL<DPP>(a, a64, xA[k], lane, skip);
    rescaleL<DPP>(a, a64, logZ);
    #pragma unroll
    for (int k = 8; k < 16; ++k) fstepL<DPP>(a, a64, xA[k], lane, skip);
    rescaleL<DPP>(a, a64, logZ);
    for (int c = 1; c <= 5; c += 2) {
        LOAD16F(xA, (c + 1) * 16);
        #pragma unroll
        for (int k = 0; k < 8; ++k) fstepL<DPP>(a, a64, xB[k], lane, skip);
        rescaleL<DPP>(a, a64, logZ);
        #pragma unroll
        for (int k = 8; k < 16; ++k) fstepL<DPP>(a, a64, xB[k], lane, skip);
        rescaleL<DPP>(a, a64, logZ);
        LOAD16F(xB, (c + 2) * 16);
        #pragma unroll
        for (int k = 0; k < 8; ++k) fstepL<DPP>(a, a64, xA[k], lane, skip);
        rescaleL<DPP>(a, a64, logZ);
        #pragma unroll
        for (int k = 8; k < 16; ++k) fstepL<DPP>(a, a64, xA[k], lane, skip);
        rescaleL<DPP>(a, a64, logZ);
    }
    #pragma unroll
    for (int k = 0; k < 8; ++k) fstepL<DPP>(a, a64, xB[k], lane, skip);
    rescaleL<DPP>(a, a64, logZ);
    #pragma unroll
    for (int k = 8; k < 16; ++k) fstepL<DPP>(a, a64, xB[k], lane, skip);
    rescaleL<DPP>(a, a64, logZ);
    a_o = a; a64_o = a64; lz_o = logZ;
}
// ---------- backward half: t = 255 (init) down to 128 ------------------------
template<bool DPP>
__device__ __forceinline__ void bwd_half(const __half* gp, int lane, bool skipT,
                                         int L, float& B_o, float& b64_o, float& lz_o) {
    bool l63 = (lane == 63);
    float xA[16], xB[16];
    LOAD16F(xA, 240); LOAD16F(xB, 224);
    int twoL = 2 * L;
    float p255 = xA[15];
    float B   = ((lane == twoL) || (L > 0 && lane == twoL - 1)) ? p255 : 0.f;
    float b64 = (twoL == 64) ? readlane0f(p255) : 0.f;
    float logZ = 0.f;
    #pragma unroll
    for (int k = 1; k < 8; ++k) bstepL<DPP>(B, b64, xA[15 - k], lane, skipT, l63);
    rescaleL<DPP>(B, b64, logZ);
    #pragma unroll
    for (int k = 8; k < 16; ++k) bstepL<DPP>(B, b64, xA[15 - k], lane, skipT, l63);
    rescaleL<DPP>(B, b64, logZ);
    for (int c = 1; c <= 5; c += 2) {
        LOAD16F(xA, 240 - (c + 1) * 16);
        #pragma unroll
        for (int k = 0; k < 8; ++k) bstepL<DPP>(B, b64, xB[15 - k], lane, skipT, l63);
        rescaleL<DPP>(B, b64, logZ);
        #pragma unroll
        for (int k = 8; k < 16; ++k) bstepL<DPP>(B, b64, xB[15 - k], lane, skipT, l63);
        rescaleL<DPP>(B, b64, logZ);
        LOAD16F(xB, 240 - (c + 2) * 16);
        #pragma unroll
        for (int k = 0; k < 8; ++k) bstepL<DPP>(B, b64, xA[15 - k], lane, skipT, l63);
        rescaleL<DPP>(B, b64, logZ);
        #pragma unroll
        for (int k = 8; k < 16; ++k) bstepL<DPP>(B, b64, xA[15 - k], lane, skipT, l63);
        rescaleL<DPP>(B, b64, logZ);
    }
    #pragma unroll
    for (int k = 0; k < 8; ++k) bstepL<DPP>(B, b64, xB[15 - k], lane, skipT, l63);
    rescaleL<DPP>(B, b64, logZ);
    #pragma unroll
    for (int k = 8; k < 16; ++k) bstepL<DPP>(B, b64, xB[15 - k], lane, skipT, l63);
    rescaleL<DPP>(B, b64, logZ);
    B_o = B; b64_o = b64; lz_o = logZ;
}

// ---------------------------------------------------------------------------
// Fused kernel: one block (512 thr, 8 waves) per example.
// Phase 1 (8 waves): stream 256 rows, p = exp(x)/sumexp, scatter 33 label-
// slot p's (fp16) into LDS lph[t][36] (72 B window per t).
// Phase 2: wave0 = forward alpha (linear, rescaled), wave1 = backward beta,
// reading LDS. Seam: loss = -(log(sum a*Bex + a64*B64) + lzA + lzB).
// No early returns around barriers.
// ---------------------------------------------------------------------------
__global__ void __launch_bounds__(512) fused_kernel(const float* __restrict__ yp,
                                                    const int* __restrict__ yt,
                                                    float* __restrict__ loss) {
    __shared__ __half lph[T_ * RSTR];    // 18,432 B
    __shared__ int    firstOwner[128];
    __shared__ int    owner[33];
    __shared__ float  alphaS[65], BS[66];
    __shared__ float  lzA, lzB;

    int tid  = threadIdx.x;
    int w    = tid >> 6;
    int lane = tid & 63;
    int li   = lane & 31;
    int b    = blockIdx.x;
    const int* lab = yt + b * LMAX;

    if (tid < 128) firstOwner[tid] = DUMP;

    // runtime DPP probes (wave-uniform; shfl fallback)
    float ptst = halfsum_dpp((float)(lane + 1));
    bool sumok = __all(readlanef(ptst, 31) == 528.0f &&
                       readlanef(ptst, 63) == 1552.0f) != 0;
    int pr = dpp0i<0x138>(lane + 1);
    bool shrok = __all(pr == ((lane == 0) ? 0 : lane)) != 0;
    int pl = dpp0i<0x130>(lane + 1);
    bool shlok = __all(pl == ((lane == 63) ? 0 : lane + 2)) != 0;
    float fsv = wavesum_dpp((float)(lane + 1));
    bool fullok = __all(fsv == 2080.0f) != 0;

    __syncthreads();
    if (tid < 33) {
        int c = (tid == 0) ? (C_ - 1) : min(max(lab[tid - 1], 0), C_ - 1);
        atomicMin(&firstOwner[c], tid);
    }
    __syncthreads();
    if (tid < 33) {
        int c = (tid == 0) ? (C_ - 1) : min(max(lab[tid - 1], 0), C_ - 1);
        owner[tid] = firstOwner[c];
    }
    int s0 = firstOwner[4 * li + 0];
    int s1 = firstOwner[4 * li + 1];
    int s2 = firstOwner[4 * li + 2];
    int s3 = firstOwner[4 * li + 3];

    // phase 1: wave w streams rows [w*32, w*32+32), 16 chunks of 2 rows
    const float4* srcQ = (const float4*)(yp + ((size_t)b * T_ + w * 32) * C_);
    int rbase = w * 32 + (lane >> 5);

    #define PROC(V, I, HS) {                                                   \
        float e0 = __expf(fminf((V).x, 80.f)), e1 = __expf(fminf((V).y, 80.f));\
        float e2 = __expf(fminf((V).z, 80.f)), e3 = __expf(fminf((V).w, 80.f));\
        float tt = HS(e0 + e1 + e2 + e3);                                      \
        float ss = (lane < 32) ? readlanef(tt, 31) : readlanef(tt, 63);        \
        float rinv = __builtin_amdgcn_rcpf(ss);                                \
        int R = (rbase + 2 * (I)) * RSTR;                                      \
        if (s0 != DUMP) lph[R + s0] = __float2half_rn(e0 * rinv);              \
        if (s1 != DUMP) lph[R + s1] = __float2half_rn(e1 * rinv);              \
        if (s2 != DUMP) lph[R + s2] = __float2half_rn(e2 * rinv);              \
        if (s3 != DUMP) lph[R + s3] = __float2half_rn(e3 * rinv); }
    #define LOOP(HS) {                                                         \
        float4 u0 = srcQ[lane], u1 = srcQ[64 + lane],                          \
               u2 = srcQ[128 + lane], u3 = srcQ[192 + lane];                   \
        _Pragma("unroll")                                                      \
        for (int ii = 0; ii < 4; ++ii) {                                       \
            float4 n0, n1, n2, n3;                                             \
            if (ii < 3) {                                                      \
                n0 = srcQ[(ii * 4 + 4) * 64 + lane];                           \
                n1 = srcQ[(ii * 4 + 5) * 64 + lane];                           \
                n2 = srcQ[(ii * 4 + 6) * 64 + lane];                           \
                n3 = srcQ[(ii * 4 + 7) * 64 + lane];                           \
            }                                                                  \
            PROC(u0, ii * 4 + 0, HS); PROC(u1, ii * 4 + 1, HS);                \
            PROC(u2, ii * 4 + 2, HS); PROC(u3, ii * 4 + 3, HS);                \
            if (ii < 3) { u0 = n0; u1 = n1; u2 = n2; u3 = n3; }                \
        } }

    if (sumok) LOOP(halfsum_dpp)
    else       LOOP(halfsum_shfl)
    #undef LOOP
    #undef PROC

    __syncthreads();

    // phase 2: wave 0 forward, wave 1 backward (waves 2-7 idle to barrier)
    int myl = (lane < LMAX) ? lab[lane] : 99;
    unsigned long long bal = __ballot(lane < LMAX && myl != 99);
    int L = __popcll(bal);
    int  j2  = lane >> 1;
    bool odd = (lane & 1) != 0;
    int  myslot = odd ? (1 + j2) : 0;

    if (w == 0) {
        const __half* gp = &lph[owner[myslot]];
        bool skip = odd && (lab[j2] != ((j2 > 0) ? lab[j2 - 1] : (C_ - 1)));
        float a, a64, lz;
        if (shrok && fullok) fwd_half<true >(gp, lane, skip, L, a, a64, lz);
        else                 fwd_half<false>(gp, lane, skip, L, a, a64, lz);
        alphaS[lane] = a;
        if (lane == 0) { alphaS[64] = a64; lzA = lz; }
    } else if (w == 1) {
        const __half* gp = &lph[owner[myslot]];
        bool skipT = odd && (lane <= 61) && (lab[min(j2 + 1, 31)] != lab[j2]);
        float Bv, b64, lz;
        if (shlok && fullok) bwd_half<true >(gp, lane, skipT, L, Bv, b64, lz);
        else                 bwd_half<false>(gp, lane, skipT, L, Bv, b64, lz);
        BS[lane] = Bv;
        if (lane == 0) { BS[64] = b64; BS[65] = 0.f; lzB = lz; }
    }
    __syncthreads();

    if (w == 0) {
        bool skipT = odd && (lane <= 61) && (lab[min(j2 + 1, 31)] != lab[j2]);
        float bex = BS[lane] + BS[lane + 1] + (skipT ? BS[lane + 2] : 0.f);
        float contrib = alphaS[lane] * bex;
        if (lane == 0) contrib += alphaS[64] * BS[64];
        #pragma unroll
        for (int off = 32; off; off >>= 1) contrib += __shfl_xor(contrib, off);
        if (lane == 0) loss[b] = -(__logf(fmaxf(contrib, 1e-37f)) + lzA + lzB);
    }
}

// ---------------------------------------------------------------------------
// mean of per-example losses -> d_out[0]
// ---------------------------------------------------------------------------
__global__ void __launch_bounds__(256) reduce_kernel(const float* __restrict__ loss,
                                                     float* __restrict__ out) {
    __shared__ float ps[4];
    int t = threadIdx.x;
    float4 v = ((const float4*)loss)[t];
    float s = v.x + v.y + v.z + v.w;
    #pragma unroll
    for (int off = 32; off; off >>= 1) s += __shfl_xor(s, off);
    if ((t & 63) == 0) ps[t >> 6] = s;
    __syncthreads();
    if (t == 0) out[0] = (ps[0] + ps[1] + ps[2] + ps[3]) * (1.0f / B_);
}

extern "C" void kernel_launch(void* const* d_in, const int* in_sizes, int n_in,
                              void* d_out, int out_size, void* d_ws, size_t ws_size,
                              hipStream_t stream) {
    const int*   yt  = (const int*)d_in[0];
    const float* yp  = (const float*)d_in[1];
    float*       out = (float*)d_out;
    float*       loss = (float*)d_ws;          // [B] floats

    fused_kernel<<<B_, 512, 0, stream>>>(yp, yt, loss);
    reduce_kernel<<<1, 256, 0, stream>>>(loss, out);
}